// Round 4
// baseline (547.971 us; speedup 1.0000x reference)
//
#include <hip/hip_runtime.h>
#include <hip/hip_bf16.h>

#define T_ 128
#define N_ 1024
#define E_ 16384
#define D_ 256
#define H_ 8
#define D2_ 512   // 2*D
#define NB_ 128   // edge buckets (src>>3): 8 src rows x 1024 dst = 8K floats (32KB)

typedef __attribute__((ext_vector_type(8))) short bf16x8;
typedef __attribute__((ext_vector_type(4))) float f32x4;

__device__ __forceinline__ void atomAddF(float* p, float v) {
#if defined(__HIP_PLATFORM_AMD__)
    unsafeAtomicAdd(p, v);
#else
    atomicAdd(p, v);
#endif
}

__device__ __forceinline__ unsigned short f2bf(float x) {
    return __bfloat16_as_ushort(__float2bfloat16(x));
}

// ---------------------------------------------------------------------------
// Kernel A0: cast W1 (f32 [256][512]) to bf16 in B-fragment-linear layout:
// W1S[k>>3][col][k&7]  (ushort).
// ---------------------------------------------------------------------------
__global__ __launch_bounds__(256)
void k_w1cast(const float* __restrict__ W1, unsigned short* __restrict__ W1S)
{
    const int u   = blockIdx.x * 256 + threadIdx.x;  // 0..16383
    const int col = u & 511;
    const int k8  = u >> 9;                          // 0..31
    unsigned short h[8];
    #pragma unroll
    for (int j = 0; j < 8; ++j)
        h[j] = f2bf(W1[(size_t)(k8 * 8 + j) * D2_ + col]);
    uint4 pk;
    pk.x = h[0] | ((unsigned)h[1] << 16);
    pk.y = h[2] | ((unsigned)h[3] << 16);
    pk.z = h[4] | ((unsigned)h[5] << 16);
    pk.w = h[6] | ((unsigned)h[7] << 16);
    *(uint4*)&W1S[(size_t)k8 * 4096 + col * 8] = pk;
}

// ---------------------------------------------------------------------------
// Kernel A: bf16 MFMA GEMM  h = relu(emb@W1+b1), fused in-register pooling.
// ---------------------------------------------------------------------------
__global__ __launch_bounds__(512)
void k_mlp1_mfma(const float* __restrict__ emb,
                 const unsigned short* __restrict__ W1S,
                 const float* __restrict__ b1,
                 float* __restrict__ pool_sum,        // [T][512]
                 unsigned int* __restrict__ pool_max) // [T][512] float-as-uint
{
    __shared__ unsigned short A_l[2048];   // [4 kb][64 row][8]  4 KB
    __shared__ unsigned short B_l[16384];  // [4 kb][512 col][8] 32 KB

    const int tid  = threadIdx.x;
    const int lane = tid & 63;
    const int wave = tid >> 6;
    const int wm = wave >> 2, wn = wave & 3;   // 2 x 4 wave grid
    const int l15 = lane & 15, l4 = lane >> 4;
    const int r0 = blockIdx.x * 64;            // global row = t*1024 + n
    const int t  = blockIdx.x >> 4;

    f32x4 acc[2][8] = {};

    for (int ks = 0; ks < 8; ++ks) {
        {
            const int row = tid >> 3, k4 = tid & 7;
            const float4 v = *(const float4*)&emb[(size_t)(r0 + row) * D_ + ks * 32 + k4 * 4];
            uint2 pk;
            pk.x = f2bf(v.x) | ((unsigned)f2bf(v.y) << 16);
            pk.y = f2bf(v.z) | ((unsigned)f2bf(v.w) << 16);
            *(uint2*)&A_l[(k4 >> 1) * 512 + row * 8 + (k4 & 1) * 4] = pk;
        }
        {
            const char* gsrc = (const char*)W1S + (size_t)ks * 32768;
            #pragma unroll
            for (int r = 0; r < 4; ++r) {
                const int off = r * 8192 + tid * 16;
                __builtin_amdgcn_global_load_lds(
                    (const __attribute__((address_space(1))) unsigned int*)(gsrc + off),
                    (__attribute__((address_space(3))) unsigned int*)((char*)B_l + off),
                    16, 0, 0);
            }
        }
        __syncthreads();

        const bf16x8 a0 = *(const bf16x8*)&A_l[l4 * 512 + (wm * 32 + l15) * 8];
        const bf16x8 a1 = *(const bf16x8*)&A_l[l4 * 512 + (wm * 32 + 16 + l15) * 8];
        #pragma unroll
        for (int cf = 0; cf < 8; ++cf) {
            const bf16x8 b = *(const bf16x8*)&B_l[l4 * 4096 + (wn * 128 + cf * 16 + l15) * 8];
            acc[0][cf] = __builtin_amdgcn_mfma_f32_16x16x32_bf16(a0, b, acc[0][cf], 0, 0, 0);
            acc[1][cf] = __builtin_amdgcn_mfma_f32_16x16x32_bf16(a1, b, acc[1][cf], 0, 0, 0);
        }
        __syncthreads();
    }

    #pragma unroll
    for (int cf = 0; cf < 8; ++cf) {
        const int col = wn * 128 + cf * 16 + l15;
        const float bias = b1[col];
        float cs = 0.f, cm = 0.f;
        #pragma unroll
        for (int mf = 0; mf < 2; ++mf) {
            #pragma unroll
            for (int j = 0; j < 4; ++j) {
                float h = acc[mf][cf][j] + bias;
                h = fmaxf(h, 0.f);
                cs += h;
                cm = fmaxf(cm, h);
            }
        }
        cs += __shfl_xor(cs, 16);
        cs += __shfl_xor(cs, 32);
        cm = fmaxf(cm, __shfl_xor(cm, 16));
        cm = fmaxf(cm, __shfl_xor(cm, 32));
        if (l4 == 0) {
            atomAddF(pool_sum + t * D2_ + col, cs);
            atomicMax(pool_max + t * D2_ + col, __float_as_uint(cm));
        }
    }
}

// ---------------------------------------------------------------------------
// Kernel B: pooled = sum/N + max ; x = relu(pooled@W2 + b2) + pos_enc
// ---------------------------------------------------------------------------
__global__ __launch_bounds__(256)
void k_mlp2(const float* __restrict__ pool_sum,
            const unsigned int* __restrict__ pool_max,
            const float* __restrict__ W2,
            const float* __restrict__ b2,
            float* __restrict__ x)
{
    __shared__ float pl[D2_];
    const int t = blockIdx.x;
    const int j = threadIdx.x;
    for (int u = j; u < D2_; u += 256)
        pl[u] = pool_sum[t * D2_ + u] * (1.0f / (float)N_) +
                __uint_as_float(pool_max[t * D2_ + u]);
    __syncthreads();

    float acc = b2[j];
    for (int k = 0; k < D2_; ++k)
        acc += pl[k] * W2[(size_t)k * D_ + j];
    acc = fmaxf(acc, 0.f);

    const int i2 = (j >> 1) * 2;
    const float div = expf((float)i2 * (-logf(10000.0f) / (float)D_));
    const float ang = (float)t * div;
    acc += (j & 1) ? cosf(ang) : sinf(ang);
    x[t * D_ + j] = acc;
}

// ---------------------------------------------------------------------------
// Kernel C: q = (x@Wq+bq)*hd^-0.5 ; k = x@Wk+bk
// ---------------------------------------------------------------------------
__global__ __launch_bounds__(256)
void k_qk(const float* __restrict__ x,
          const float* __restrict__ Wq, const float* __restrict__ bq,
          const float* __restrict__ Wk, const float* __restrict__ bk,
          float* __restrict__ q, float* __restrict__ k)
{
    __shared__ float xl[D_];
    const int t = blockIdx.x;
    const int j = threadIdx.x;
    xl[j] = x[t * D_ + j];
    __syncthreads();

    float aq = bq[j], ak = bk[j];
    for (int kk = 0; kk < D_; ++kk) {
        const float xv = xl[kk];
        aq += xv * Wq[(size_t)kk * D_ + j];
        ak += xv * Wk[(size_t)kk * D_ + j];
    }
    q[t * D_ + j] = aq * 0.17677669529663687f;  // (D/H)^-0.5
    k[t * D_ + j] = ak;
}

// ---------------------------------------------------------------------------
// Kernel D: scores -> per-head softmax -> mean heads -> threshold/identity/tril
// ---------------------------------------------------------------------------
__global__ __launch_bounds__(128)
void k_probs(const float* __restrict__ q,
             const float* __restrict__ k,
             float* __restrict__ probs)
{
    __shared__ float ql[D_];
    __shared__ float red[128];
    const int qt = blockIdx.x;
    const int kt = threadIdx.x;

    ql[kt]       = q[qt * D_ + kt];
    ql[kt + 128] = q[qt * D_ + kt + 128];
    __syncthreads();

    float sh[H_];
    #pragma unroll
    for (int h = 0; h < H_; ++h) {
        float s = 0.f;
        #pragma unroll
        for (int d = 0; d < 32; ++d)
            s += ql[h * 32 + d] * k[kt * D_ + h * 32 + d];
        sh[h] = s;
    }

    float pm = 0.f;
    for (int h = 0; h < H_; ++h) {
        red[kt] = sh[h]; __syncthreads();
        for (int off = 64; off > 0; off >>= 1) {
            if (kt < off) red[kt] = fmaxf(red[kt], red[kt + off]);
            __syncthreads();
        }
        const float m = red[0]; __syncthreads();
        const float e = expf(sh[h] - m);
        red[kt] = e; __syncthreads();
        for (int off = 64; off > 0; off >>= 1) {
            if (kt < off) red[kt] += red[kt + off];
            __syncthreads();
        }
        const float Z = red[0]; __syncthreads();
        pm += e / Z;
    }
    pm *= (1.0f / (float)H_);

    if (pm < (1.0f / (float)T_)) pm = 0.f;
    if (kt == qt) pm += 1.0f;
    if (kt > qt) pm = 0.f;
    probs[qt * T_ + kt] = pm;
}

// ---------------------------------------------------------------------------
// Kernel E1: counting-sort each snapshot's edges into NB_=128 src-buckets
// (bucket = src>>3). sorted[s*E+i] = ((src<<10)|dst, val).
// boffT[b][s] (transposed) so k_accum setup loads coalesce; boffT[NB_][s]=E_.
// ---------------------------------------------------------------------------
__global__ __launch_bounds__(256)
void k_bucket(const float* __restrict__ edge_val,
              const int* __restrict__ edge_src,
              const int* __restrict__ edge_dst,
              uint2* __restrict__ sorted,
              int* __restrict__ boffT)
{
    __shared__ int hist[NB_];
    __shared__ int boffs[NB_ + 1];
    __shared__ int cur[NB_];
    const int s = blockIdx.x;
    const int tid = threadIdx.x;

    if (tid < NB_) hist[tid] = 0;
    __syncthreads();
    for (int e = tid; e < E_; e += 256)
        atomicAdd(&hist[edge_src[(size_t)s * E_ + e] >> 3], 1);
    __syncthreads();
    if (tid == 0) {
        int run = 0;
        for (int b = 0; b < NB_; ++b) { boffs[b] = run; run += hist[b]; }
        boffs[NB_] = run;   // == E_
    }
    __syncthreads();
    if (tid < NB_ + 1) boffT[tid * T_ + s] = boffs[tid];
    if (tid < NB_) cur[tid] = boffs[tid];
    __syncthreads();
    for (int e = tid; e < E_; e += 256) {
        const size_t eo = (size_t)s * E_ + e;
        const int src = edge_src[eo];
        const int dst = edge_dst[eo];
        const float v = edge_val[eo];
        const int idx = atomicAdd(&cur[src >> 3], 1);
        sorted[(size_t)s * E_ + idx] = make_uint2((unsigned)((src << 10) | dst),
                                                  __float_as_uint(v));
    }
}

// ---------------------------------------------------------------------------
// Kernel E2: block (b, t) owns out[t, b*8..b*8+7, :] (8K floats, 32KB LDS).
// Flat (s,e) iteration: prefix-scan of active-s bucket counts, then one long
// loop with a 7-step LDS binary search per item -> independent iterations.
// 32KB accum -> 4 blocks/CU (16 waves) for latency hiding.
// ---------------------------------------------------------------------------
__global__ __launch_bounds__(256)
void k_accum(const float* __restrict__ probs,
             const uint2* __restrict__ sorted,
             const int* __restrict__ boffT,
             float* __restrict__ out)
{
    __shared__ float acc[8 * 1024];     // 32 KB
    __shared__ float pv[T_];            // probs[t][s] (0 if inactive)
    __shared__ int   gbase[T_];         // s*E_ + bucket start
    __shared__ int   sc[T_];            // scan scratch (inclusive prefix)
    __shared__ int   pref[T_ + 1];      // exclusive prefix of counts
    const int b   = blockIdx.x;
    const int t   = blockIdx.y;
    const int tid = threadIdx.x;

    {
        float4* a4 = (float4*)acc;
        #pragma unroll
        for (int i = 0; i < 8; ++i)
            a4[i * 256 + tid] = make_float4(0.f, 0.f, 0.f, 0.f);
    }

    // --- setup: per-s count of this bucket's edges (0 if s>t or p==0)
    int c = 0;
    if (tid < T_) {
        const int s = tid;
        float p = (s <= t) ? probs[t * T_ + s] : 0.f;
        pv[s] = p;
        int g = 0;
        if (p != 0.f) {
            const int e0 = boffT[b * T_ + s];        // coalesced across s
            const int e1 = boffT[(b + 1) * T_ + s];
            c = e1 - e0;
            g = s * E_ + e0;
        }
        gbase[s] = g;
        sc[s] = c;
    }
    __syncthreads();
    // --- Hillis-Steele inclusive scan over 128 counts
    #pragma unroll
    for (int off = 1; off < T_; off <<= 1) {
        int v = 0;
        if (tid < T_ && tid >= off) v = sc[tid - off];
        __syncthreads();
        if (tid < T_) sc[tid] += v;
        __syncthreads();
    }
    if (tid < T_) pref[tid + 1] = sc[tid];
    if (tid == 0) pref[0] = 0;
    __syncthreads();

    const int tot = pref[T_];
    #pragma unroll 2
    for (int i = tid; i < tot; i += 256) {
        // binary search: largest s with pref[s] <= i  (7 steps for 128 segs)
        int lo = 0, hi = T_;
        #pragma unroll
        for (int st = 0; st < 7; ++st) {
            const int mid = (lo + hi) >> 1;
            const bool ge = (pref[mid] <= i);
            lo = ge ? mid : lo;
            hi = ge ? hi : mid;
        }
        const uint2 kv = sorted[(size_t)(gbase[lo] + (i - pref[lo]))];
        atomicAdd(&acc[kv.x & 8191], pv[lo] * __uint_as_float(kv.y));
    }
    __syncthreads();

    float4* o4 = (float4*)(out + ((size_t)t << 20) + ((size_t)b << 13));
    const float4* a4 = (const float4*)acc;
    #pragma unroll
    for (int i = 0; i < 8; ++i)
        o4[i * 256 + tid] = a4[i * 256 + tid];
}

// ---------------------------------------------------------------------------
extern "C" void kernel_launch(void* const* d_in, const int* in_sizes, int n_in,
                              void* d_out, int out_size, void* d_ws, size_t ws_size,
                              hipStream_t stream) {
    const float* emb      = (const float*)d_in[0];
    const float* W1       = (const float*)d_in[1];
    const float* b1       = (const float*)d_in[2];
    const float* W2       = (const float*)d_in[3];
    const float* b2       = (const float*)d_in[4];
    const float* Wq       = (const float*)d_in[5];
    const float* bq       = (const float*)d_in[6];
    const float* Wk       = (const float*)d_in[7];
    const float* bk       = (const float*)d_in[8];
    const float* edge_val = (const float*)d_in[9];
    const int*   edge_src = (const int*)d_in[10];
    const int*   edge_dst = (const int*)d_in[11];
    float* out = (float*)d_out;

    // workspace layout (~17.3 MB)
    char* ws = (char*)d_ws;
    float*          pool_sum = (float*)(ws);                      // 256 KB
    unsigned int*   pool_max = (unsigned int*)(ws + (256 << 10)); // 256 KB
    float*          x        = (float*)(ws + (512 << 10));        // 128 KB
    float*          q        = (float*)(ws + (640 << 10));        // 128 KB
    float*          k        = (float*)(ws + (768 << 10));        // 128 KB
    float*          probs    = (float*)(ws + (896 << 10));        // 64 KB
    int*            boffT    = (int*)(ws + (960 << 10));          // 65 KB
    unsigned short* W1S      = (unsigned short*)(ws + (1056 << 10)); // 256 KB
    uint2*          sorted   = (uint2*)(ws + (1312 << 10));       // 16 MB

    hipMemsetAsync(d_ws, 0, 512 << 10, stream);   // zero pool accumulators

    k_w1cast<<<64, 256, 0, stream>>>(W1, W1S);
    k_mlp1_mfma<<<2048, 512, 0, stream>>>(emb, W1S, b1, pool_sum, pool_max);
    k_mlp2<<<128, 256, 0, stream>>>(pool_sum, pool_max, W2, b2, x);
    k_qk<<<128, 256, 0, stream>>>(x, Wq, bq, Wk, bk, q, k);
    k_probs<<<128, 128, 0, stream>>>(q, k, probs);
    k_bucket<<<T_, 256, 0, stream>>>(edge_val, edge_src, edge_dst, sorted, boffT);
    k_accum<<<dim3(NB_, T_), 256, 0, stream>>>(probs, sorted, boffT, out);
}